// Round 2
// 826.370 us; speedup vs baseline: 1.5569x; 1.5569x over previous
//
#include <hip/hip_runtime.h>

typedef unsigned int uint_t;

#define N_NODES 100000
#define N_EDGES 1600000
#define D 64
#define D2 4096   // D*D
#define D3 12288  // 3*D2

#define NPAD 100352u  // N_NODES rounded up

// ---------- workspace layout (4-byte units) ----------
#define OFF_GI1   0u
#define OFF_GI2   (OFF_GI1 + D3)
#define OFF_GH1   (OFF_GI2 + D3)
#define OFF_GH2   (OFF_GH1 + D3)
#define OFF_W1    (OFF_GH2 + D3)          // 49152
#define OFF_W2    (OFF_W1 + D2)           // 53248
#define OFF_DEG   (OFF_W2 + D2)           // 57344   int[NPAD]
#define OFF_CTR   (OFF_DEG + NPAD)        // 157696  int[1] (padded 64)
#define OFF_NORM  (OFF_CTR + 64u)         // 157760  float[NPAD]
#define OFF_ROWS  (OFF_NORM + NPAD)       // 258112  int[NPAD] rowstart
#define OFF_CUR   (OFF_ROWS + NPAD)       // 358464  int[NPAD] cursor (==rowend after build)
#define OFF_CSR   (OFF_CUR + NPAD)        // 458816  int[N_EDGES] src sorted by dst-bucket
#define OFF_H     (OFF_CSR + 1600000u)    // 2058816 float[N*D]
#define OFF_AGG1  (OFF_H + 6400000u)      // 8458816 float[N*D]
// total: OFF_AGG1 + 6400000 = 14,858,816 units ~= 59.4 MiB of ws

__device__ __forceinline__ float dot4(float4 a, float4 b, float acc) {
    acc = fmaf(a.x, b.x, acc);
    acc = fmaf(a.y, b.y, acc);
    acc = fmaf(a.z, b.z, acc);
    acc = fmaf(a.w, b.w, acc);
    return acc;
}

__device__ __forceinline__ float waveReduce(float v) {
#pragma unroll
    for (int off = 32; off > 0; off >>= 1) v += __shfl_down(v, off, 64);
    return v;
}

// K1: 4 matvecs in one pass over w_ih,w_hh (fp32). One block per row (12288 rows).
__global__ __launch_bounds__(256) void gru_matvec(
    const float* __restrict__ w_ih, const float* __restrict__ w_hh,
    const float* __restrict__ x1, const float* __restrict__ x2,
    const float* __restrict__ h1, const float* __restrict__ h2,
    float* __restrict__ gi1, float* __restrict__ gi2,
    float* __restrict__ gh1, float* __restrict__ gh2)
{
    const int row = blockIdx.x;
    const int tid = threadIdx.x;
    const float4* wi  = (const float4*)(w_ih + (size_t)row * D2);
    const float4* wh  = (const float4*)(w_hh + (size_t)row * D2);
    const float4* vx1 = (const float4*)x1;
    const float4* vx2 = (const float4*)x2;
    const float4* vh1 = (const float4*)h1;
    const float4* vh2 = (const float4*)h2;

    float ai1 = 0.f, ai2 = 0.f, ah1 = 0.f, ah2 = 0.f;
#pragma unroll
    for (int c = 0; c < 4; ++c) {
        int idx = tid + c * 256;          // 1024 float4 per row
        float4 a  = wi[idx];
        ai1 = dot4(a, vx1[idx], ai1);
        ai2 = dot4(a, vx2[idx], ai2);
        float4 b  = wh[idx];
        ah1 = dot4(b, vh1[idx], ah1);
        ah2 = dot4(b, vh2[idx], ah2);
    }
    ai1 = waveReduce(ai1);
    ai2 = waveReduce(ai2);
    ah1 = waveReduce(ah1);
    ah2 = waveReduce(ah2);

    __shared__ float red[4][4];
    const int wave = tid >> 6, lane = tid & 63;
    if (lane == 0) {
        red[wave][0] = ai1; red[wave][1] = ai2;
        red[wave][2] = ah1; red[wave][3] = ah2;
    }
    __syncthreads();
    if (tid < 4) {
        float s = red[0][tid] + red[1][tid] + red[2][tid] + red[3][tid];
        float* outp = (tid == 0) ? gi1 : (tid == 1) ? gi2 : (tid == 2) ? gh1 : gh2;
        outp[row] = s;
    }
}

// K2: GRU gates -> evolved weights w1,w2 (fp32, 4096 each)
__global__ __launch_bounds__(256) void gru_gates(
    const float* __restrict__ gi1, const float* __restrict__ gh1,
    const float* __restrict__ gi2, const float* __restrict__ gh2,
    const float* __restrict__ b_ih, const float* __restrict__ b_hh,
    const float* __restrict__ hw1, const float* __restrict__ hw2,
    float* __restrict__ w1, float* __restrict__ w2)
{
    const int j = blockIdx.x * 256 + threadIdx.x;   // 0..4095
    const int layer = blockIdx.y;
    const float* gi = layer ? gi2 : gi1;
    const float* gh = layer ? gh2 : gh1;
    const float* hw = layer ? hw2 : hw1;
    float* wo = layer ? w2 : w1;

    float ir = gi[j]          + b_ih[j];
    float hr = gh[j]          + b_hh[j];
    float iz = gi[j + D2]     + b_ih[j + D2];
    float hz = gh[j + D2]     + b_hh[j + D2];
    float in_ = gi[j + 2*D2]  + b_ih[j + 2*D2];
    float hn = gh[j + 2*D2]   + b_hh[j + 2*D2];

    float r = 1.f / (1.f + expf(-(ir + hr)));
    float z = 1.f / (1.f + expf(-(iz + hz)));
    float n = tanhf(in_ + r * hn);
    wo[j] = (1.f - z) * n + z * hw[j];
}

// K3: in-degree via int atomics
__global__ __launch_bounds__(256) void deg_kernel(
    const int* __restrict__ dst, int* __restrict__ deg)
{
    int e = blockIdx.x * 256 + threadIdx.x;
    if (e < N_EDGES) atomicAdd(&deg[dst[e]], 1);
}

// K4: norm = clip(deg,1)^-0.5, plus CSR bucket offsets.
// Bucket ORDER is irrelevant (output indexed by node), so offsets come from a
// global counter; wave-level prefix-sum -> only 1 atomic per wave.
// NOTE: all __shfl here execute convergently (guards only wrap the adds).
__global__ __launch_bounds__(256) void norm_offset_kernel(
    const int* __restrict__ deg, float* __restrict__ norm,
    int* __restrict__ rowstart, int* __restrict__ cursor,
    int* __restrict__ counter)
{
    const int n = blockIdx.x * 256 + threadIdx.x;
    const int lane = threadIdx.x & 63;
    const int dg = (n < N_NODES) ? deg[n] : 0;

    // inclusive wave prefix sum of dg
    int pre = dg;
#pragma unroll
    for (int off = 1; off < 64; off <<= 1) {
        int t = __shfl_up(pre, off, 64);
        if (lane >= off) pre += t;
    }
    int waveTotal = __shfl(pre, 63, 64);
    int base = 0;
    if (lane == 63) base = atomicAdd(counter, waveTotal);
    base = __shfl(base, 63, 64);

    if (n < N_NODES) {
        int st = base + pre - dg;   // exclusive prefix
        rowstart[n] = st;
        cursor[n]   = st;
        norm[n] = 1.0f / sqrtf(fmaxf((float)dg, 1.0f));
    }
}

// K5: bucket edges by dst. cursor[d] ends at rowstart[d]+deg[d] == rowend.
__global__ __launch_bounds__(256) void build_csr_kernel(
    const int* __restrict__ src, const int* __restrict__ dst,
    int* __restrict__ cursor, int* __restrict__ csr_src)
{
    int e = blockIdx.x * 256 + threadIdx.x;
    if (e >= N_EDGES) return;
    int d = dst[e];
    int pos = atomicAdd(&cursor[d], 1);
    csr_src[pos] = src[e];
}

// K6/K8: dense transform out[node] = (relu?)(x[node]) @ w, w staged in LDS
template <bool RELU>
__global__ __launch_bounds__(256) void transform_kernel(
    const float* __restrict__ xin, const float* __restrict__ w,
    float* __restrict__ out)
{
    __shared__ float sw[D * D];
    const int tid = threadIdx.x;
#pragma unroll
    for (int i = 0; i < 16; ++i) sw[tid + i * 256] = w[tid + i * 256];
    __syncthreads();

    const int node = blockIdx.x * 256 + tid;
    if (node >= N_NODES) return;

    float x[D];
    const float4* p = (const float4*)(xin + (size_t)node * D);
#pragma unroll
    for (int i = 0; i < 16; ++i) {
        float4 u = p[i];
        x[i * 4 + 0] = u.x; x[i * 4 + 1] = u.y;
        x[i * 4 + 2] = u.z; x[i * 4 + 3] = u.w;
    }
    if (RELU) {
#pragma unroll
        for (int k = 0; k < D; ++k) x[k] = fmaxf(x[k], 0.f);
    }

    float acc[D];
#pragma unroll
    for (int j = 0; j < D; ++j) acc[j] = 0.f;
#pragma unroll
    for (int k = 0; k < D; ++k) {
        float a = x[k];
#pragma unroll
        for (int j = 0; j < D; ++j) acc[j] = fmaf(a, sw[k * D + j], acc[j]);
    }

    float4* po = (float4*)(out + (size_t)node * D);
#pragma unroll
    for (int i = 0; i < 16; ++i)
        po[i] = make_float4(acc[i*4], acc[i*4+1], acc[i*4+2], acc[i*4+3]);
}

// K7/K9: gather aggregation. One wave per node, NO atomics.
// acc = sum_{e in bucket(n)} h[src_e] * norm[src_e];  out[n] = acc * norm[n]
// 16 lanes x float4 cover one h-row (256B); 4 edges in flight per iteration.
// CORRECTNESS: every __shfl executes with a wave-UNIFORM trip count (iters),
// so all 64 lanes are active at the shfl and all source lanes (kk<=63) are
// active. Out-of-range batch lanes carry w=0, so even an unpredicated
// contribution would be zero; the kk<nb predicate only skips work.
__global__ __launch_bounds__(256) void aggregate_gather(
    const float* __restrict__ h, const int* __restrict__ csr_src,
    const int* __restrict__ rowstart, const int* __restrict__ rowend,
    const float* __restrict__ norm, float* __restrict__ out)
{
    const int node = blockIdx.x * 4 + (threadIdx.x >> 6);
    if (node >= N_NODES) return;
    const int lane = threadIdx.x & 63;
    const int grp  = lane >> 4;       // which of 4 concurrent edges
    const int lg   = lane & 15;       // column-quad within the row

    const int beg = rowstart[node];
    const int end = rowend[node];

    float4 acc = make_float4(0.f, 0.f, 0.f, 0.f);
    for (int base = beg; base < end; base += 64) {
        // batch-load up to 64 edge records, broadcast via shfl
        int p = base + lane;
        int idx = 0; float w = 0.f;
        if (p < end) { idx = csr_src[p]; w = norm[idx]; }
        const int nb = min(64, end - base);
        const int iters = (nb + 3) >> 2;     // wave-uniform
        for (int i = 0; i < iters; ++i) {
            const int kk = i * 4 + grp;      // <= 63 always
            int s    = __shfl(idx, kk, 64);  // convergent shfl
            float ww = __shfl(w,  kk, 64);
            if (kk < nb) {
                const float4 hv = *(const float4*)(h + (size_t)s * D + lg * 4);
                acc.x = fmaf(hv.x, ww, acc.x);
                acc.y = fmaf(hv.y, ww, acc.y);
                acc.z = fmaf(hv.z, ww, acc.z);
                acc.w = fmaf(hv.w, ww, acc.w);
            }
        }
    }
    // fold the 4 edge-groups: lanes l, l+16, l+32, l+48 hold the same columns
#pragma unroll
    for (int off = 32; off >= 16; off >>= 1) {
        acc.x += __shfl_down(acc.x, off, 64);
        acc.y += __shfl_down(acc.y, off, 64);
        acc.z += __shfl_down(acc.z, off, 64);
        acc.w += __shfl_down(acc.w, off, 64);
    }
    if (lane < 16) {
        const float nn = norm[node];
        float4 o = make_float4(acc.x * nn, acc.y * nn, acc.z * nn, acc.w * nn);
        *(float4*)(out + (size_t)node * D + (size_t)lane * 4) = o;
    }
}

extern "C" void kernel_launch(void* const* d_in, const int* in_sizes, int n_in,
                              void* d_out, int out_size, void* d_ws, size_t ws_size,
                              hipStream_t stream)
{
    const float* emb  = (const float*)d_in[0];
    const float* gc1w = (const float*)d_in[1];
    const float* gc2w = (const float*)d_in[2];
    const float* gc1h = (const float*)d_in[3];
    const float* gc2h = (const float*)d_in[4];
    const float* w_ih = (const float*)d_in[5];
    const float* w_hh = (const float*)d_in[6];
    const float* b_ih = (const float*)d_in[7];
    const float* b_hh = (const float*)d_in[8];
    const int* src = (const int*)d_in[9];
    const int* dst = (const int*)d_in[10];

    float* ws = (float*)d_ws;
    float* gi1 = ws + OFF_GI1;
    float* gi2 = ws + OFF_GI2;
    float* gh1 = ws + OFF_GH1;
    float* gh2 = ws + OFF_GH2;
    float* w1  = ws + OFF_W1;
    float* w2  = ws + OFF_W2;
    int*   deg = (int*)(ws + OFF_DEG);
    int*   ctr = (int*)(ws + OFF_CTR);
    float* nrm = ws + OFF_NORM;
    int*   rows = (int*)(ws + OFF_ROWS);
    int*   cur  = (int*)(ws + OFF_CUR);
    int*   csr  = (int*)(ws + OFF_CSR);
    float* h    = ws + OFF_H;
    float* agg1 = ws + OFF_AGG1;
    float* out  = (float*)d_out;

    // only the degree array + counter need zeroing (~400 KB)
    hipMemsetAsync(deg, 0, NPAD * sizeof(int), stream);
    hipMemsetAsync(ctr, 0, sizeof(int), stream);

    // GRU weight evolution: x = hist, hidden = current weights
    gru_matvec<<<D3, 256, 0, stream>>>(w_ih, w_hh, gc1h, gc2h, gc1w, gc2w,
                                       gi1, gi2, gh1, gh2);
    gru_gates<<<dim3(16, 2), 256, 0, stream>>>(gi1, gh1, gi2, gh2,
                                               b_ih, b_hh, gc1w, gc2w, w1, w2);

    // degree + norm + CSR-by-dst (built once, reused by both layers)
    deg_kernel<<<(N_EDGES + 255) / 256, 256, 0, stream>>>(dst, deg);
    norm_offset_kernel<<<(N_NODES + 255) / 256, 256, 0, stream>>>(
        deg, nrm, rows, cur, ctr);
    build_csr_kernel<<<(N_EDGES + 255) / 256, 256, 0, stream>>>(src, dst, cur, csr);

    // layer 1
    transform_kernel<false><<<(N_NODES + 255) / 256, 256, 0, stream>>>(emb, w1, h);
    aggregate_gather<<<(N_NODES + 3) / 4, 256, 0, stream>>>(h, csr, rows, cur, nrm, agg1);

    // layer 2 (relu applied to layer-1 aggregate inside the transform)
    transform_kernel<true><<<(N_NODES + 255) / 256, 256, 0, stream>>>(agg1, w2, h);
    aggregate_gather<<<(N_NODES + 3) / 4, 256, 0, stream>>>(h, csr, rows, cur, nrm, out);
}